// Round 10
// baseline (117.703 us; speedup 1.0000x reference)
//
#include <hip/hip_runtime.h>

#define N_NODES 100000
#define N_EDGES 3200000
#define DIN     128
#define DOUT    64
#define GEMM_BLOCKS 1563   /* ceil(100000/64) */
#define RP_BLOCKS   12500  /* 3.2M/256 */

typedef unsigned short bf16_t;
typedef float f32x4  __attribute__((ext_vector_type(4)));
typedef short bf16x8 __attribute__((ext_vector_type(8)));

__device__ __forceinline__ bf16_t f32_to_bf16(float f) {
    union { float f; unsigned int u; } un; un.f = f;
    unsigned int u = un.u + 0x7fffu + ((un.u >> 16) & 1u);  // RNE
    return (bf16_t)(u >> 16);
}
__device__ __forceinline__ unsigned int pack2(float lo, float hi) {
    return (unsigned int)f32_to_bf16(lo) | ((unsigned int)f32_to_bf16(hi) << 16);
}
__device__ __forceinline__ float2 bf16x2_to_f32x2(unsigned int p) {
    union { unsigned int u; float f; } lo, hi;
    lo.u = p << 16;
    hi.u = p & 0xffff0000u;
    return make_float2(lo.f, hi.f);
}

#define UNPACK_FMA(ACC, G, VV)                                    \
    do {                                                          \
        const float2 _f0 = bf16x2_to_f32x2((G).x);                \
        const float2 _f1 = bf16x2_to_f32x2((G).y);                \
        const float2 _f2 = bf16x2_to_f32x2((G).z);                \
        const float2 _f3 = bf16x2_to_f32x2((G).w);                \
        ACC[0] += (VV) * _f0.x; ACC[1] += (VV) * _f0.y;           \
        ACC[2] += (VV) * _f1.x; ACC[3] += (VV) * _f1.y;           \
        ACC[4] += (VV) * _f2.x; ACC[5] += (VV) * _f2.y;           \
        ACC[6] += (VV) * _f3.x; ACC[7] += (VV) * _f3.y;           \
    } while (0)

// one masked 16-edge group (dead slots: clamped index, v=0)
#define MASKED_GROUP16(ACC, EBASE)                                      \
    do {                                                                \
        const int   _ei = (EBASE) + grp;                                \
        const bool  _ok = _ei < end;                                    \
        const int   _ec = _ok ? _ei : (end - 1);                        \
        const int   _cc = cols[_ec];                                    \
        const float _vv = _ok ? vals[_ec] : 0.f;                        \
        const uint4 _g  = *(const uint4*)&xh[(size_t)_cc * 32 + 8 * fq];\
        UNPACK_FMA(ACC, _g, _vv);                                       \
    } while (0)

// ---------------------------------------------------------------------------
// Kernel 1 (heterogeneous grid): blocks [0, GEMM_BLOCKS) = MFMA GEMM
// xw_bf16 = bf16(x @ W) written in SPLIT-HALF layout:
//   half0 (features 0..31)  at xwb[node*32 + f]
//   half1 (features 32..63) at xwb[N*32 + node*32 + (f-32)]
// blocks [GEMM_BLOCKS, +RP_BLOCKS) build row_ptr from sorted rows.
// ---------------------------------------------------------------------------
__global__ __launch_bounds__(256) void gemm_rowptr(const float* __restrict__ x,
                                                   const float* __restrict__ w,
                                                   const int*   __restrict__ rows,
                                                   bf16_t* __restrict__ xwb,
                                                   int* __restrict__ row_ptr) {
    __shared__ unsigned short Xs[64][DIN];  // 16 KB bf16, chunk-swizzled
    __shared__ unsigned short Wt[DOUT][DIN];// 16 KB bf16, W transposed, swizzled

    const int bid = blockIdx.x;
    const int tid = threadIdx.x;

    if (bid >= GEMM_BLOCKS) {
        // ---- row_ptr builder ----
        const int e = (bid - GEMM_BLOCKS) * 256 + tid;
        if (e < N_EDGES) {
            const int cur  = rows[e];
            const int prev = (e == 0) ? -1 : rows[e - 1];
            for (int r = prev + 1; r <= cur; ++r) row_ptr[r] = e;
            if (e == N_EDGES - 1)
                for (int r = cur + 1; r <= N_NODES; ++r) row_ptr[r] = N_EDGES;
        }
        return;
    }

    const int block_row = bid * 64;

    // stage Wt[n][k] (transpose of W), coalesced float4 reads
    {
        const float4* w4 = (const float4*)w;
#pragma unroll
        for (int i = 0; i < 8; ++i) {
            const int f4 = i * 256 + tid;       // 0..2047
            const float4 v = w4[f4];
            const int base = f4 * 4;
            const int k = base >> 6;            // row of W
            const int n = base & 63;            // col (multiple of 4)
            Wt[n + 0][(((k >> 3) ^ ((n + 0) & 7)) << 3) | (k & 7)] = f32_to_bf16(v.x);
            Wt[n + 1][(((k >> 3) ^ ((n + 1) & 7)) << 3) | (k & 7)] = f32_to_bf16(v.y);
            Wt[n + 2][(((k >> 3) ^ ((n + 2) & 7)) << 3) | (k & 7)] = f32_to_bf16(v.z);
            Wt[n + 3][(((k >> 3) ^ ((n + 3) & 7)) << 3) | (k & 7)] = f32_to_bf16(v.w);
        }
    }
    // stage Xs: 4 threads per row, each converts 32 fp32 -> 4 16B chunks
    {
        const int r = tid >> 2;
        const int q = tid & 3;
        const int gr = block_row + r;
        const float4* xp = (const float4*)&x[(size_t)gr * DIN + q * 32];
        const bool ok = gr < N_NODES;
#pragma unroll
        for (int ci = 0; ci < 4; ++ci) {
            float4 a = make_float4(0.f, 0.f, 0.f, 0.f), b = a;
            if (ok) { a = xp[2 * ci]; b = xp[2 * ci + 1]; }
            uint4 pk;
            pk.x = pack2(a.x, a.y);
            pk.y = pack2(a.z, a.w);
            pk.z = pack2(b.x, b.y);
            pk.w = pack2(b.z, b.w);
            const int c = q * 4 + ci;
            *(uint4*)&Xs[r][(c ^ (r & 7)) << 3] = pk;
        }
    }
    __syncthreads();

    const int wv_ = tid >> 6;
    const int l   = tid & 63;
    const int lr  = l & 15;
    const int hi  = l >> 4;
    const int arow = wv_ * 16 + lr;

    f32x4 acc0 = {0.f, 0.f, 0.f, 0.f};
    f32x4 acc1 = acc0, acc2 = acc0, acc3 = acc0;
#pragma unroll
    for (int s = 0; s < 4; ++s) {
        const int kc = s * 4 + hi;
        const bf16x8 a  = *(const bf16x8*)&Xs[arow][(kc ^ (arow & 7)) << 3];
        const int bc = (kc ^ (lr & 7)) << 3;
        const bf16x8 b0 = *(const bf16x8*)&Wt[lr     ][bc];
        const bf16x8 b1 = *(const bf16x8*)&Wt[16 + lr][bc];
        const bf16x8 b2 = *(const bf16x8*)&Wt[32 + lr][bc];
        const bf16x8 b3 = *(const bf16x8*)&Wt[48 + lr][bc];
        acc0 = __builtin_amdgcn_mfma_f32_16x16x32_bf16(a, b0, acc0, 0, 0, 0);
        acc1 = __builtin_amdgcn_mfma_f32_16x16x32_bf16(a, b1, acc1, 0, 0, 0);
        acc2 = __builtin_amdgcn_mfma_f32_16x16x32_bf16(a, b2, acc2, 0, 0, 0);
        acc3 = __builtin_amdgcn_mfma_f32_16x16x32_bf16(a, b3, acc3, 0, 0, 0);
    }

#pragma unroll
    for (int reg = 0; reg < 4; ++reg) {
        const int grow = block_row + wv_ * 16 + hi * 4 + reg;
        if (grow < N_NODES) {
            bf16_t* o0 = &xwb[(size_t)grow * 32 + lr];                        // half 0
            bf16_t* o1 = &xwb[(size_t)N_NODES * 32 + (size_t)grow * 32 + lr]; // half 1
            o0[0]  = f32_to_bf16(acc0[reg]);
            o0[16] = f32_to_bf16(acc1[reg]);
            o1[0]  = f32_to_bf16(acc2[reg]);
            o1[16] = f32_to_bf16(acc3[reg]);
        }
    }
}

// ---------------------------------------------------------------------------
// Kernel 2: SpMM + combine, SPLIT-HALF. One wave = one row x one 32-feature
// half. grp = lane>>2 picks edge slot (16 per group!), fq = lane&3 picks the
// feature octet within the half. One dwordx4 gather covers 16 edges; avg row
// = 32 edges = 2 gathers + 2 cols + 2 vals, all independent. Working set per
// half = 6.4 MB (vs 4 MiB/XCD L2); waves of half 0 dispatch before half 1.
// Reduce: shfl_xor 4/8/16/32.
// ---------------------------------------------------------------------------
__global__ __launch_bounds__(256) void spmm_half(const bf16_t* __restrict__ xwb,
                                                 const int*    __restrict__ row_ptr,
                                                 const int*    __restrict__ cols,
                                                 const float*  __restrict__ vals,
                                                 const float*  __restrict__ h0,
                                                 const float*  __restrict__ bias,
                                                 float* __restrict__ out) {
    const int wid  = (blockIdx.x * blockDim.x + threadIdx.x) >> 6;
    const int lane = threadIdx.x & 63;
    if (wid >= 2 * N_NODES) return;

    const int half = (wid >= N_NODES) ? 1 : 0;
    const int row  = __builtin_amdgcn_readfirstlane(wid - half * N_NODES);

    const int grp = lane >> 2;   // edge slot within group of 16
    const int fq  = lane & 3;    // feature octet within the 32-feature half

    const bf16_t* xh = xwb + (size_t)half * N_NODES * 32;
    const int fbase = half * 32 + 8 * fq;   // global feature base for this lane

    const int start = __builtin_amdgcn_readfirstlane(row_ptr[row]);
    const int end   = __builtin_amdgcn_readfirstlane(row_ptr[row + 1]);

    const f32x4 ha = __builtin_nontemporal_load((const f32x4*)&h0[(size_t)row * DOUT + fbase]);
    const f32x4 hb = __builtin_nontemporal_load((const f32x4*)&h0[(size_t)row * DOUT + fbase + 4]);
    const f32x4 ba = *(const f32x4*)&bias[fbase];
    const f32x4 bb = *(const f32x4*)&bias[fbase + 4];

    float accA[8] = {};
    float accB[8] = {};
    int e = start;

    // main: 32 edges / iter = 2 independent 16-edge gathers in flight
    for (; e + 32 <= end; e += 32) {
        const int   c0 = cols[e + grp];
        const int   c1 = cols[e + 16 + grp];
        const float v0 = vals[e + grp];
        const float v1 = vals[e + 16 + grp];
        const uint4 g0 = *(const uint4*)&xh[(size_t)c0 * 32 + 8 * fq];
        const uint4 g1 = *(const uint4*)&xh[(size_t)c1 * 32 + 8 * fq];
        UNPACK_FMA(accA, g0, v0);
        UNPACK_FMA(accB, g1, v1);
    }
    // masked tail: 16 edges / iter
    for (; e < end; e += 16) {
        MASKED_GROUP16(accA, e);
    }

    // butterfly reduce across the 16 edge-groups (lane stride 4)
    float s0, s1, s2, s3, s4, s5, s6, s7;
#define RED(SJ, J)                                       \
    do {                                                 \
        float _t = accA[J] + accB[J];                    \
        _t += __shfl_xor(_t, 4, 64);                     \
        _t += __shfl_xor(_t, 8, 64);                     \
        _t += __shfl_xor(_t, 16, 64);                    \
        _t += __shfl_xor(_t, 32, 64);                    \
        SJ = _t;                                         \
    } while (0)
    RED(s0, 0); RED(s1, 1); RED(s2, 2); RED(s3, 3);
    RED(s4, 4); RED(s5, 5); RED(s6, 6); RED(s7, 7);
#undef RED

    if (grp == 0) {
        f32x4 ra, rb;
        ra.x = 0.9f * s0 + 0.1f * ha.x + ba.x;
        ra.y = 0.9f * s1 + 0.1f * ha.y + ba.y;
        ra.z = 0.9f * s2 + 0.1f * ha.z + ba.z;
        ra.w = 0.9f * s3 + 0.1f * ha.w + ba.w;
        rb.x = 0.9f * s4 + 0.1f * hb.x + bb.x;
        rb.y = 0.9f * s5 + 0.1f * hb.y + bb.y;
        rb.z = 0.9f * s6 + 0.1f * hb.z + bb.z;
        rb.w = 0.9f * s7 + 0.1f * hb.w + bb.w;
        __builtin_nontemporal_store(ra, (f32x4*)&out[(size_t)row * DOUT + fbase]);
        __builtin_nontemporal_store(rb, (f32x4*)&out[(size_t)row * DOUT + fbase + 4]);
    }
}

extern "C" void kernel_launch(void* const* d_in, const int* in_sizes, int n_in,
                              void* d_out, int out_size, void* d_ws, size_t ws_size,
                              hipStream_t stream) {
    const float* x    = (const float*)d_in[0];
    const int*   rows = (const int*)  d_in[1];
    const int*   cols = (const int*)  d_in[2];
    const float* vals = (const float*)d_in[3];
    const float* h0   = (const float*)d_in[4];
    const float* w    = (const float*)d_in[5];
    const float* bias = (const float*)d_in[6];
    float* out = (float*)d_out;

    bf16_t* xwb = (bf16_t*)d_ws;                         // 2 halves x N*32 bf16 = 12.8 MB
    const size_t xw_bytes = (size_t)N_NODES * DOUT * sizeof(bf16_t);
    int* row_ptr = (int*)((char*)d_ws + xw_bytes);       // (N+1) ints = 400 KB

    gemm_rowptr<<<GEMM_BLOCKS + RP_BLOCKS, 256, 0, stream>>>(x, w, rows, xwb, row_ptr);
    // 2*N_NODES waves, 4 waves per 256-thread block
    spmm_half<<<(2 * N_NODES + 3) / 4, 256, 0, stream>>>(
        xwb, row_ptr, cols, vals, h0, bias, out);
}

// Round 11
// 103.692 us; speedup vs baseline: 1.1351x; 1.1351x over previous
//
#include <hip/hip_runtime.h>

#define N_NODES 100000
#define N_EDGES 3200000
#define DIN     128
#define DOUT    64
#define GEMM_BLOCKS 1563   /* ceil(100000/64) */
#define RP_BLOCKS   12500  /* 3.2M/256 */

typedef unsigned short bf16_t;
typedef float f32x4  __attribute__((ext_vector_type(4)));
typedef short bf16x8 __attribute__((ext_vector_type(8)));

__device__ __forceinline__ bf16_t f32_to_bf16(float f) {
    union { float f; unsigned int u; } un; un.f = f;
    unsigned int u = un.u + 0x7fffu + ((un.u >> 16) & 1u);  // RNE
    return (bf16_t)(u >> 16);
}
__device__ __forceinline__ unsigned int pack2(float lo, float hi) {
    return (unsigned int)f32_to_bf16(lo) | ((unsigned int)f32_to_bf16(hi) << 16);
}
__device__ __forceinline__ float2 bf16x2_to_f32x2(unsigned int p) {
    union { unsigned int u; float f; } lo, hi;
    lo.u = p << 16;
    hi.u = p & 0xffff0000u;
    return make_float2(lo.f, hi.f);
}

#define UNPACK_FMA(ACC, G, VV)                                    \
    do {                                                          \
        const float2 _f0 = bf16x2_to_f32x2((G).x);                \
        const float2 _f1 = bf16x2_to_f32x2((G).y);                \
        const float2 _f2 = bf16x2_to_f32x2((G).z);                \
        const float2 _f3 = bf16x2_to_f32x2((G).w);                \
        ACC[0] += (VV) * _f0.x; ACC[1] += (VV) * _f0.y;           \
        ACC[2] += (VV) * _f1.x; ACC[3] += (VV) * _f1.y;           \
        ACC[4] += (VV) * _f2.x; ACC[5] += (VV) * _f2.y;           \
        ACC[6] += (VV) * _f3.x; ACC[7] += (VV) * _f3.y;           \
    } while (0)

// one masked 8-edge octet group; dead slots clamp to edge 0 (one hot line), v=0
#define MGROUP(ACC, EBASE, END)                                             \
    do {                                                                    \
        const int   _ei = (EBASE) + grp;                                    \
        const bool  _ok = _ei < (END);                                      \
        const int   _ec = _ok ? _ei : 0;                                    \
        const int   _cc = cols[_ec];                                        \
        const float _vv = _ok ? vals[_ec] : 0.f;                            \
        const uint4 _g  = *(const uint4*)&xwb[(size_t)_cc * DOUT + 8 * fq]; \
        UNPACK_FMA(ACC, _g, _vv);                                           \
    } while (0)

// ---------------------------------------------------------------------------
// Kernel 1 (heterogeneous grid): blocks [0, GEMM_BLOCKS) = MFMA GEMM
// xw_bf16 = bf16(x @ W), interleaved layout xwb[node*64+f];
// blocks [GEMM_BLOCKS, +RP_BLOCKS) build row_ptr from the sorted rows array.
// ---------------------------------------------------------------------------
__global__ __launch_bounds__(256) void gemm_rowptr(const float* __restrict__ x,
                                                   const float* __restrict__ w,
                                                   const int*   __restrict__ rows,
                                                   bf16_t* __restrict__ xwb,
                                                   int* __restrict__ row_ptr) {
    __shared__ unsigned short Xs[64][DIN];  // 16 KB bf16, chunk-swizzled
    __shared__ unsigned short Wt[DOUT][DIN];// 16 KB bf16, W transposed, swizzled

    const int bid = blockIdx.x;
    const int tid = threadIdx.x;

    if (bid >= GEMM_BLOCKS) {
        const int e = (bid - GEMM_BLOCKS) * 256 + tid;
        if (e < N_EDGES) {
            const int cur  = rows[e];
            const int prev = (e == 0) ? -1 : rows[e - 1];
            for (int r = prev + 1; r <= cur; ++r) row_ptr[r] = e;
            if (e == N_EDGES - 1)
                for (int r = cur + 1; r <= N_NODES; ++r) row_ptr[r] = N_EDGES;
        }
        return;
    }

    const int block_row = bid * 64;

    {
        const float4* w4 = (const float4*)w;
#pragma unroll
        for (int i = 0; i < 8; ++i) {
            const int f4 = i * 256 + tid;       // 0..2047
            const float4 v = w4[f4];
            const int base = f4 * 4;
            const int k = base >> 6;            // row of W
            const int n = base & 63;            // col (multiple of 4)
            Wt[n + 0][(((k >> 3) ^ ((n + 0) & 7)) << 3) | (k & 7)] = f32_to_bf16(v.x);
            Wt[n + 1][(((k >> 3) ^ ((n + 1) & 7)) << 3) | (k & 7)] = f32_to_bf16(v.y);
            Wt[n + 2][(((k >> 3) ^ ((n + 2) & 7)) << 3) | (k & 7)] = f32_to_bf16(v.z);
            Wt[n + 3][(((k >> 3) ^ ((n + 3) & 7)) << 3) | (k & 7)] = f32_to_bf16(v.w);
        }
    }
    {
        const int r = tid >> 2;
        const int q = tid & 3;
        const int gr = block_row + r;
        const float4* xp = (const float4*)&x[(size_t)gr * DIN + q * 32];
        const bool ok = gr < N_NODES;
#pragma unroll
        for (int ci = 0; ci < 4; ++ci) {
            float4 a = make_float4(0.f, 0.f, 0.f, 0.f), b = a;
            if (ok) { a = xp[2 * ci]; b = xp[2 * ci + 1]; }
            uint4 pk;
            pk.x = pack2(a.x, a.y);
            pk.y = pack2(a.z, a.w);
            pk.z = pack2(b.x, b.y);
            pk.w = pack2(b.z, b.w);
            const int c = q * 4 + ci;
            *(uint4*)&Xs[r][(c ^ (r & 7)) << 3] = pk;
        }
    }
    __syncthreads();

    const int wv_ = tid >> 6;
    const int l   = tid & 63;
    const int lr  = l & 15;
    const int hi  = l >> 4;
    const int arow = wv_ * 16 + lr;

    f32x4 acc0 = {0.f, 0.f, 0.f, 0.f};
    f32x4 acc1 = acc0, acc2 = acc0, acc3 = acc0;
#pragma unroll
    for (int s = 0; s < 4; ++s) {
        const int kc = s * 4 + hi;
        const bf16x8 a  = *(const bf16x8*)&Xs[arow][(kc ^ (arow & 7)) << 3];
        const int bc = (kc ^ (lr & 7)) << 3;
        const bf16x8 b0 = *(const bf16x8*)&Wt[lr     ][bc];
        const bf16x8 b1 = *(const bf16x8*)&Wt[16 + lr][bc];
        const bf16x8 b2 = *(const bf16x8*)&Wt[32 + lr][bc];
        const bf16x8 b3 = *(const bf16x8*)&Wt[48 + lr][bc];
        acc0 = __builtin_amdgcn_mfma_f32_16x16x32_bf16(a, b0, acc0, 0, 0, 0);
        acc1 = __builtin_amdgcn_mfma_f32_16x16x32_bf16(a, b1, acc1, 0, 0, 0);
        acc2 = __builtin_amdgcn_mfma_f32_16x16x32_bf16(a, b2, acc2, 0, 0, 0);
        acc3 = __builtin_amdgcn_mfma_f32_16x16x32_bf16(a, b3, acc3, 0, 0, 0);
    }

#pragma unroll
    for (int reg = 0; reg < 4; ++reg) {
        const int grow = block_row + wv_ * 16 + hi * 4 + reg;
        if (grow < N_NODES) {
            bf16_t* o = &xwb[(size_t)grow * DOUT + lr];
            o[0]  = f32_to_bf16(acc0[reg]);
            o[16] = f32_to_bf16(acc1[reg]);
            o[32] = f32_to_bf16(acc2[reg]);
            o[48] = f32_to_bf16(acc3[reg]);
        }
    }
}

// ---------------------------------------------------------------------------
// Kernel 2: SpMM + combine, TWO rows per wave, STRAIGHT-LINE.
// grp = lane>>3 (edge slot in octet), fq = lane&7 (feature octet).
// Per row: 6 masked octet-groups cover deg<=48 (P[deg>48] ~ 0.2% at
// Poisson(32)); both rows' 12 groups live in ONE basic block so the compiler
// interleaves all 12 gathers + 24 index loads across the two rows.
// Dead slots clamp to edge 0 -> 8 lanes share one hot line (~0 traffic).
// Rare deg>48 handled by masked loops. Butterfly all-reduce (shfl_xor
// 8/16/32); grp==0 lanes store row0, grp==1 lanes store row1.
// ---------------------------------------------------------------------------
__global__ __launch_bounds__(256) void spmm_pair(const bf16_t* __restrict__ xwb,
                                                 const int*    __restrict__ row_ptr,
                                                 const int*    __restrict__ cols,
                                                 const float*  __restrict__ vals,
                                                 const float*  __restrict__ h0,
                                                 const float*  __restrict__ bias,
                                                 float* __restrict__ out) {
    const int wid  = (blockIdx.x * blockDim.x + threadIdx.x) >> 6;
    const int lane = threadIdx.x & 63;
    const int r0 = wid << 1;
    if (r0 >= N_NODES) return;   // N_NODES even -> r0+1 always valid here

    const int grp = lane >> 3;
    const int fq  = lane & 7;

    const int s0 = __builtin_amdgcn_readfirstlane(row_ptr[r0]);
    const int m0 = __builtin_amdgcn_readfirstlane(row_ptr[r0 + 1]);
    const int e1 = __builtin_amdgcn_readfirstlane(row_ptr[r0 + 2]);

    // grp==0 lanes own row0's store, grp==1 own row1's
    const int rsel = r0 + (grp == 1 ? 1 : 0);
    const f32x4 ha = __builtin_nontemporal_load((const f32x4*)&h0[(size_t)rsel * DOUT + 8 * fq]);
    const f32x4 hb = __builtin_nontemporal_load((const f32x4*)&h0[(size_t)rsel * DOUT + 8 * fq + 4]);
    const f32x4 ba = *(const f32x4*)&bias[8 * fq];
    const f32x4 bb = *(const f32x4*)&bias[8 * fq + 4];

    float accA[8] = {};
    float accB[8] = {};

    // straight-line: 6 masked groups per row, interleaved across the two rows
    MGROUP(accA, s0,      m0);  MGROUP(accB, m0,      e1);
    MGROUP(accA, s0 + 8,  m0);  MGROUP(accB, m0 + 8,  e1);
    MGROUP(accA, s0 + 16, m0);  MGROUP(accB, m0 + 16, e1);
    MGROUP(accA, s0 + 24, m0);  MGROUP(accB, m0 + 24, e1);
    MGROUP(accA, s0 + 32, m0);  MGROUP(accB, m0 + 32, e1);
    MGROUP(accA, s0 + 40, m0);  MGROUP(accB, m0 + 40, e1);

    // rare overflow (deg > 48), wave-uniform trip counts
    for (int e = s0 + 48; e < m0; e += 8) MGROUP(accA, e, m0);
    for (int e = m0 + 48; e < e1; e += 8) MGROUP(accB, e, e1);

    // butterfly all-reduce across the 8 edge-groups (xor 8/16/32)
    float a0, a1, a2, a3, a4, a5, a6, a7;
    float b0, b1, b2, b3, b4, b5, b6, b7;
#define RED(ACC, J, S)                                   \
    do {                                                 \
        float _t = ACC[J];                               \
        _t += __shfl_xor(_t, 8, 64);                     \
        _t += __shfl_xor(_t, 16, 64);                    \
        _t += __shfl_xor(_t, 32, 64);                    \
        S = _t;                                          \
    } while (0)
    RED(accA, 0, a0); RED(accA, 1, a1); RED(accA, 2, a2); RED(accA, 3, a3);
    RED(accA, 4, a4); RED(accA, 5, a5); RED(accA, 6, a6); RED(accA, 7, a7);
    RED(accB, 0, b0); RED(accB, 1, b1); RED(accB, 2, b2); RED(accB, 3, b3);
    RED(accB, 4, b4); RED(accB, 5, b5); RED(accB, 6, b6); RED(accB, 7, b7);
#undef RED

    if (grp < 2) {
        const bool g1 = (grp == 1);
        const float t0 = g1 ? b0 : a0;
        const float t1 = g1 ? b1 : a1;
        const float t2 = g1 ? b2 : a2;
        const float t3 = g1 ? b3 : a3;
        const float t4 = g1 ? b4 : a4;
        const float t5 = g1 ? b5 : a5;
        const float t6 = g1 ? b6 : a6;
        const float t7 = g1 ? b7 : a7;
        f32x4 ra, rb;
        ra.x = 0.9f * t0 + 0.1f * ha.x + ba.x;
        ra.y = 0.9f * t1 + 0.1f * ha.y + ba.y;
        ra.z = 0.9f * t2 + 0.1f * ha.z + ba.z;
        ra.w = 0.9f * t3 + 0.1f * ha.w + ba.w;
        rb.x = 0.9f * t4 + 0.1f * hb.x + bb.x;
        rb.y = 0.9f * t5 + 0.1f * hb.y + bb.y;
        rb.z = 0.9f * t6 + 0.1f * hb.z + bb.z;
        rb.w = 0.9f * t7 + 0.1f * hb.w + bb.w;
        __builtin_nontemporal_store(ra, (f32x4*)&out[(size_t)rsel * DOUT + 8 * fq]);
        __builtin_nontemporal_store(rb, (f32x4*)&out[(size_t)rsel * DOUT + 8 * fq + 4]);
    }
}

extern "C" void kernel_launch(void* const* d_in, const int* in_sizes, int n_in,
                              void* d_out, int out_size, void* d_ws, size_t ws_size,
                              hipStream_t stream) {
    const float* x    = (const float*)d_in[0];
    const int*   rows = (const int*)  d_in[1];
    const int*   cols = (const int*)  d_in[2];
    const float* vals = (const float*)d_in[3];
    const float* h0   = (const float*)d_in[4];
    const float* w    = (const float*)d_in[5];
    const float* bias = (const float*)d_in[6];
    float* out = (float*)d_out;

    bf16_t* xwb = (bf16_t*)d_ws;                         // N*DOUT bf16 = 12.8 MB
    const size_t xw_bytes = (size_t)N_NODES * DOUT * sizeof(bf16_t);
    int* row_ptr = (int*)((char*)d_ws + xw_bytes);       // (N+1) ints = 400 KB

    gemm_rowptr<<<GEMM_BLOCKS + RP_BLOCKS, 256, 0, stream>>>(x, w, rows, xwb, row_ptr);
    // N/2 waves, 4 waves per 256-thread block
    spmm_pair<<<(N_NODES / 2 + 3) / 4, 256, 0, stream>>>(
        xwb, row_ptr, cols, vals, h0, bias, out);
}

// Round 12
// 94.732 us; speedup vs baseline: 1.2425x; 1.0946x over previous
//
#include <hip/hip_runtime.h>

#define N_NODES 100000
#define N_EDGES 3200000
#define DIN     128
#define DOUT    64
#define GEMM_BLOCKS 1563   /* ceil(100000/64) */
#define RP_BLOCKS   12500  /* 3.2M/256 */

typedef unsigned short u16;
typedef _Float16 f16;
typedef _Float16 f16x2 __attribute__((ext_vector_type(2)));
typedef _Float16 f16x8 __attribute__((ext_vector_type(8)));
typedef float    f32x4 __attribute__((ext_vector_type(4)));

__device__ __forceinline__ u16 f32_to_f16u(float f) {
    return __builtin_bit_cast(u16, (f16)f);   // RNE
}
__device__ __forceinline__ unsigned int pack2h(float lo, float hi) {
    return (unsigned int)f32_to_f16u(lo) | ((unsigned int)f32_to_f16u(hi) << 16);
}

// 8 f16 features (uint4) * scalar -> 8 f32 accumulators, via v_fma_mix
#define UNPACK_FMA(ACC, G, VV)                                        \
    do {                                                              \
        const f16x2 _h0 = __builtin_bit_cast(f16x2, (G).x);           \
        const f16x2 _h1 = __builtin_bit_cast(f16x2, (G).y);           \
        const f16x2 _h2 = __builtin_bit_cast(f16x2, (G).z);           \
        const f16x2 _h3 = __builtin_bit_cast(f16x2, (G).w);           \
        ACC[0] += (float)_h0.x * (VV); ACC[1] += (float)_h0.y * (VV); \
        ACC[2] += (float)_h1.x * (VV); ACC[3] += (float)_h1.y * (VV); \
        ACC[4] += (float)_h2.x * (VV); ACC[5] += (float)_h2.y * (VV); \
        ACC[6] += (float)_h3.x * (VV); ACC[7] += (float)_h3.y * (VV); \
    } while (0)

// one masked 8-edge group (dead slots: clamp to start, v=0); requires start<end
#define MASKED_GROUP(ACC, EBASE)                                            \
    do {                                                                    \
        const int   _ei = (EBASE) + grp;                                    \
        const bool  _ok = _ei < end;                                        \
        const int   _ec = _ok ? _ei : start;                                \
        const int   _cc = cols[_ec];                                        \
        const float _vv = _ok ? vals[_ec] : 0.f;                            \
        const uint4 _g  = *(const uint4*)&xwb[(size_t)_cc * DOUT + 8 * fq]; \
        UNPACK_FMA(ACC, _g, _vv);                                           \
    } while (0)

// ---------------------------------------------------------------------------
// Kernel 1 (heterogeneous grid): blocks [0, GEMM_BLOCKS) = f16 MFMA GEMM
// xw_f16 = f16(x @ W), layout xwb[node*64+f];
// blocks [GEMM_BLOCKS, +RP_BLOCKS) build row_ptr from the sorted rows array.
// ---------------------------------------------------------------------------
__global__ __launch_bounds__(256) void gemm_rowptr(const float* __restrict__ x,
                                                   const float* __restrict__ w,
                                                   const int*   __restrict__ rows,
                                                   u16* __restrict__ xwb,
                                                   int* __restrict__ row_ptr) {
    __shared__ u16 Xs[64][DIN];   // 16 KB f16, chunk-swizzled
    __shared__ u16 Wt[DOUT][DIN]; // 16 KB f16, W transposed, swizzled

    const int bid = blockIdx.x;
    const int tid = threadIdx.x;

    if (bid >= GEMM_BLOCKS) {
        const int e = (bid - GEMM_BLOCKS) * 256 + tid;
        if (e < N_EDGES) {
            const int cur  = rows[e];
            const int prev = (e == 0) ? -1 : rows[e - 1];
            for (int r = prev + 1; r <= cur; ++r) row_ptr[r] = e;
            if (e == N_EDGES - 1)
                for (int r = cur + 1; r <= N_NODES; ++r) row_ptr[r] = N_EDGES;
        }
        return;
    }

    const int block_row = bid * 64;

    {
        const float4* w4 = (const float4*)w;
#pragma unroll
        for (int i = 0; i < 8; ++i) {
            const int f4 = i * 256 + tid;       // 0..2047
            const float4 v = w4[f4];
            const int base = f4 * 4;
            const int k = base >> 6;            // row of W
            const int n = base & 63;            // col (multiple of 4)
            Wt[n + 0][(((k >> 3) ^ ((n + 0) & 7)) << 3) | (k & 7)] = f32_to_f16u(v.x);
            Wt[n + 1][(((k >> 3) ^ ((n + 1) & 7)) << 3) | (k & 7)] = f32_to_f16u(v.y);
            Wt[n + 2][(((k >> 3) ^ ((n + 2) & 7)) << 3) | (k & 7)] = f32_to_f16u(v.z);
            Wt[n + 3][(((k >> 3) ^ ((n + 3) & 7)) << 3) | (k & 7)] = f32_to_f16u(v.w);
        }
    }
    {
        const int r = tid >> 2;
        const int q = tid & 3;
        const int gr = block_row + r;
        const float4* xp = (const float4*)&x[(size_t)gr * DIN + q * 32];
        const bool ok = gr < N_NODES;
#pragma unroll
        for (int ci = 0; ci < 4; ++ci) {
            float4 a = make_float4(0.f, 0.f, 0.f, 0.f), b = a;
            if (ok) { a = xp[2 * ci]; b = xp[2 * ci + 1]; }
            uint4 pk;
            pk.x = pack2h(a.x, a.y);
            pk.y = pack2h(a.z, a.w);
            pk.z = pack2h(b.x, b.y);
            pk.w = pack2h(b.z, b.w);
            const int c = q * 4 + ci;
            *(uint4*)&Xs[r][(c ^ (r & 7)) << 3] = pk;
        }
    }
    __syncthreads();

    const int wv_ = tid >> 6;
    const int l   = tid & 63;
    const int lr  = l & 15;
    const int hi  = l >> 4;
    const int arow = wv_ * 16 + lr;

    f32x4 acc0 = {0.f, 0.f, 0.f, 0.f};
    f32x4 acc1 = acc0, acc2 = acc0, acc3 = acc0;
#pragma unroll
    for (int s = 0; s < 4; ++s) {
        const int kc = s * 4 + hi;
        const f16x8 a  = *(const f16x8*)&Xs[arow][(kc ^ (arow & 7)) << 3];
        const int bc = (kc ^ (lr & 7)) << 3;
        const f16x8 b0 = *(const f16x8*)&Wt[lr     ][bc];
        const f16x8 b1 = *(const f16x8*)&Wt[16 + lr][bc];
        const f16x8 b2 = *(const f16x8*)&Wt[32 + lr][bc];
        const f16x8 b3 = *(const f16x8*)&Wt[48 + lr][bc];
        acc0 = __builtin_amdgcn_mfma_f32_16x16x32_f16(a, b0, acc0, 0, 0, 0);
        acc1 = __builtin_amdgcn_mfma_f32_16x16x32_f16(a, b1, acc1, 0, 0, 0);
        acc2 = __builtin_amdgcn_mfma_f32_16x16x32_f16(a, b2, acc2, 0, 0, 0);
        acc3 = __builtin_amdgcn_mfma_f32_16x16x32_f16(a, b3, acc3, 0, 0, 0);
    }

#pragma unroll
    for (int reg = 0; reg < 4; ++reg) {
        const int grow = block_row + wv_ * 16 + hi * 4 + reg;
        if (grow < N_NODES) {
            u16* o = &xwb[(size_t)grow * DOUT + lr];
            o[0]  = f32_to_f16u(acc0[reg]);
            o[16] = f32_to_f16u(acc1[reg]);
            o[32] = f32_to_f16u(acc2[reg]);
            o[48] = f32_to_f16u(acc3[reg]);
        }
    }
}

// ---------------------------------------------------------------------------
// Kernel 2: SpMM + combine (R8 geometry, f16 payload). One wave per row.
// grp = lane>>3 picks edge slot in group of 8; fq = lane&7 picks the feature
// octet; one dwordx4 gather covers 8 edges/instruction. Main loop: 32 edges =
// 4 independent octet-gathers in flight. f16 data consumed via v_fma_mix
// (no unpack ALU). Reduce: shfl_xor 8/16/32.
// ---------------------------------------------------------------------------
__global__ __launch_bounds__(256) void spmm_combine(const u16*   __restrict__ xwb,
                                                    const int*   __restrict__ row_ptr,
                                                    const int*   __restrict__ cols,
                                                    const float* __restrict__ vals,
                                                    const float* __restrict__ h0,
                                                    const float* __restrict__ bias,
                                                    float* __restrict__ out) {
    const int wid  = (blockIdx.x * blockDim.x + threadIdx.x) >> 6;
    const int lane = threadIdx.x & 63;
    if (wid >= N_NODES) return;

    const int grp = lane >> 3;   // edge slot within group of 8
    const int fq  = lane & 7;    // feature octet index

    const int row   = __builtin_amdgcn_readfirstlane(wid);
    const int start = __builtin_amdgcn_readfirstlane(row_ptr[row]);
    const int end   = __builtin_amdgcn_readfirstlane(row_ptr[row + 1]);

    const f32x4 ha = __builtin_nontemporal_load((const f32x4*)&h0[(size_t)row * DOUT + 8 * fq]);
    const f32x4 hb = __builtin_nontemporal_load((const f32x4*)&h0[(size_t)row * DOUT + 8 * fq + 4]);
    const f32x4 ba = *(const f32x4*)&bias[8 * fq];
    const f32x4 bb = *(const f32x4*)&bias[8 * fq + 4];

    float accA[8] = {};
    float accB[8] = {};

    if (start < end) {
        int e = start;
        // main: 32 edges / iter = 4 independent octet-gathers in flight
        for (; e + 32 <= end; e += 32) {
            const int   c0 = cols[e      + grp];
            const int   c1 = cols[e + 8  + grp];
            const int   c2 = cols[e + 16 + grp];
            const int   c3 = cols[e + 24 + grp];
            const float v0 = vals[e      + grp];
            const float v1 = vals[e + 8  + grp];
            const float v2 = vals[e + 16 + grp];
            const float v3 = vals[e + 24 + grp];
            const uint4 g0 = *(const uint4*)&xwb[(size_t)c0 * DOUT + 8 * fq];
            const uint4 g1 = *(const uint4*)&xwb[(size_t)c1 * DOUT + 8 * fq];
            const uint4 g2 = *(const uint4*)&xwb[(size_t)c2 * DOUT + 8 * fq];
            const uint4 g3 = *(const uint4*)&xwb[(size_t)c3 * DOUT + 8 * fq];
            UNPACK_FMA(accA, g0, v0);
            UNPACK_FMA(accB, g1, v1);
            UNPACK_FMA(accA, g2, v2);
            UNPACK_FMA(accB, g3, v3);
        }
        // masked tail: 16 edges / iter (2 independent masked groups)
        for (; e < end; e += 16) {
            MASKED_GROUP(accA, e);
            if (e + 8 < end) MASKED_GROUP(accB, e + 8);
        }
    }

    // butterfly reduce across the 8 edge-groups
    float s0, s1, s2, s3, s4, s5, s6, s7;
#define RED(SJ, J)                                       \
    do {                                                 \
        float _t = accA[J] + accB[J];                    \
        _t += __shfl_xor(_t, 8, 64);                     \
        _t += __shfl_xor(_t, 16, 64);                    \
        _t += __shfl_xor(_t, 32, 64);                    \
        SJ = _t;                                         \
    } while (0)
    RED(s0, 0); RED(s1, 1); RED(s2, 2); RED(s3, 3);
    RED(s4, 4); RED(s5, 5); RED(s6, 6); RED(s7, 7);
#undef RED

    if (grp == 0) {
        f32x4 ra, rb;
        ra.x = 0.9f * s0 + 0.1f * ha.x + ba.x;
        ra.y = 0.9f * s1 + 0.1f * ha.y + ba.y;
        ra.z = 0.9f * s2 + 0.1f * ha.z + ba.z;
        ra.w = 0.9f * s3 + 0.1f * ha.w + ba.w;
        rb.x = 0.9f * s4 + 0.1f * hb.x + bb.x;
        rb.y = 0.9f * s5 + 0.1f * hb.y + bb.y;
        rb.z = 0.9f * s6 + 0.1f * hb.z + bb.z;
        rb.w = 0.9f * s7 + 0.1f * hb.w + bb.w;
        __builtin_nontemporal_store(ra, (f32x4*)&out[(size_t)row * DOUT + 8 * fq]);
        __builtin_nontemporal_store(rb, (f32x4*)&out[(size_t)row * DOUT + 8 * fq + 4]);
    }
}

extern "C" void kernel_launch(void* const* d_in, const int* in_sizes, int n_in,
                              void* d_out, int out_size, void* d_ws, size_t ws_size,
                              hipStream_t stream) {
    const float* x    = (const float*)d_in[0];
    const int*   rows = (const int*)  d_in[1];
    const int*   cols = (const int*)  d_in[2];
    const float* vals = (const float*)d_in[3];
    const float* h0   = (const float*)d_in[4];
    const float* w    = (const float*)d_in[5];
    const float* bias = (const float*)d_in[6];
    float* out = (float*)d_out;

    u16* xwb = (u16*)d_ws;                               // N*DOUT f16 = 12.8 MB
    const size_t xw_bytes = (size_t)N_NODES * DOUT * sizeof(u16);
    int* row_ptr = (int*)((char*)d_ws + xw_bytes);       // (N+1) ints = 400 KB

    gemm_rowptr<<<GEMM_BLOCKS + RP_BLOCKS, 256, 0, stream>>>(x, w, rows, xwb, row_ptr);
    spmm_combine<<<(N_NODES * 64 + 255) / 256, 256, 0, stream>>>(
        xwb, row_ptr, cols, vals, h0, bias, out);
}